// Round 8
// baseline (757.249 us; speedup 1.0000x reference)
//
#include <hip/hip_runtime.h>
#include <hip/hip_bf16.h>
#include <cstddef>

#define kN 50000
#define kNP 50048   // padded to 64*782
#define kE 500000
#define kG 64
#define kDIN 64
#define kD 128
#define kH 256   // 2*D
#define kA4 512  // 4*D
#define kOUT 10
#define PCHUNK 200

typedef __attribute__((ext_vector_type(8))) short bfrag_t;
typedef __attribute__((ext_vector_type(4))) float f32x4;
union FragCast { uint4 u; bfrag_t f; };

// ---- static device scratch (rewritten per call) ----
__device__ __attribute__((aligned(16))) __hip_bfloat16 g_h [(size_t)kNP * kD];
__device__ __attribute__((aligned(16))) __hip_bfloat16 g_hc[(size_t)kNP * kD];
__device__ __attribute__((aligned(16))) __hip_bfloat16 g_z [(size_t)kNP * kD];  // agg scratch
__device__ __attribute__((aligned(16))) __hip_bfloat16 g_A [(size_t)kNP * kA4];
__device__ __attribute__((aligned(16))) __hip_bfloat16 g_B [(size_t)kNP * kA4];
__device__ __attribute__((aligned(16))) __hip_bfloat16 g_pk[1056 * 512];  // packed MFMA B-frags
__device__ float g_atts[kE];   // edge weights, CSR order
__device__ int   g_rowptr[kN + 1];
__device__ int   g_cnt[kN];
__device__ int   g_cols[kE];
__device__ float g_pool[kG * kD];
__device__ float g_gcnt[kG];

__device__ inline float bflo(unsigned u) { union { unsigned i; float f; } c; c.i = u << 16; return c.f; }
__device__ inline float bfhi(unsigned u) { union { unsigned i; float f; } c; c.i = u & 0xffff0000u; return c.f; }
__device__ inline __hip_bfloat16* bsel(int s) { return s == 0 ? g_h : (s == 1 ? g_hc : g_z); }

// ---- weight prepack: fp32 -> bf16 MFMA B-fragment order ----
// mats: [0..2] encW1(128x256) [3..5] encW2(256x128) [6..8] clfW1 [9..11] clfW2
//       [12] attTop(128x512) [13] attBot(128x512) [14] enc_in(64x128) [15] clf_in(64x128)
// B-frag (k0,n0): lane holds B[k0*32+(lane>>4)*8+j][n0*16+(lane&15)], j=0..7.
struct SrcPtrs { const float* p[16]; };

__global__ __launch_bounds__(64) void prepack_kernel(SrcPtrs sp) {
    const int fs[17] = {0,64,128,192,256,320,384,448,512,576,640,704,768,896,1024,1040,1056};
    const int Ns[16] = {256,256,256,128,128,128,256,256,256,128,128,128,512,512,128,128};
    int f = blockIdx.x;
    int m = 0;
    while (f >= fs[m + 1]) m++;
    const int fl = f - fs[m];
    const int N = Ns[m];
    const int n0 = fl % (N >> 4);
    const int k0 = fl / (N >> 4);
    const int lane = threadIdx.x;
    const int q = lane >> 4, c = lane & 15;
    const float* src = sp.p[m];
    __hip_bfloat16* dst = g_pk + (size_t)f * 512 + lane * 8;
    const int kb = k0 * 32 + q * 8;
    const int n = n0 * 16 + c;
#pragma unroll
    for (int j = 0; j < 8; j++)
        dst[j] = __float2bfloat16(src[(size_t)(kb + j) * N + n]);
}

// packed offsets (bf16 elements)
#define PK_ENC_W1(l) ((size_t)(0   + (l) * 64) * 512)
#define PK_ENC_W2(l) ((size_t)(192 + (l) * 64) * 512)
#define PK_CLF_W1(l) ((size_t)(384 + (l) * 64) * 512)
#define PK_CLF_W2(l) ((size_t)(576 + (l) * 64) * 512)
#define PK_ATT_TOP   ((size_t)768 * 512)
#define PK_ATT_BOT   ((size_t)896 * 512)
#define PK_ENC_IN    ((size_t)1024 * 512)
#define PK_CLF_IN    ((size_t)1040 * 512)

__global__ __launch_bounds__(256) void zero_prep_kernel() {
    const int i = blockIdx.x * 256 + threadIdx.x;
    if (i < kN) g_cnt[i] = 0;
    if (i < kG * kD) g_pool[i] = 0.f;
    if (i < kG) g_gcnt[i] = 0.f;
}

__global__ __launch_bounds__(256) void hist_kernel(const int* __restrict__ row) {
    const int e = blockIdx.x * 256 + threadIdx.x;
    if (e < kE) atomicAdd(&g_cnt[row[e]], 1);
}

__global__ __launch_bounds__(1024) void scan_kernel() {
    const int t = threadIdx.x;
    const int base_i = t * 49;
    int local[49];
    int s = 0;
    for (int i = 0; i < 49; i++) {
        const int idx = base_i + i;
        const int c = (idx < kN) ? g_cnt[idx] : 0;
        local[i] = s;
        s += c;
    }
    __shared__ int part[1024];
    part[t] = s;
    __syncthreads();
    for (int off = 1; off < 1024; off <<= 1) {
        int v = 0;
        if (t >= off) v = part[t - off];
        __syncthreads();
        part[t] += v;
        __syncthreads();
    }
    const int base = (t == 0) ? 0 : part[t - 1];
    for (int i = 0; i < 49; i++) {
        const int idx = base_i + i;
        if (idx < kN) {
            const int v = base + local[i];
            g_rowptr[idx] = v;
            g_cnt[idx] = v;
        }
    }
    if (t == 1023) g_rowptr[kN] = kE;
}

__global__ __launch_bounds__(256) void scatter_kernel(
    const int* __restrict__ row, const int* __restrict__ col) {
    const int e = blockIdx.x * 256 + threadIdx.x;
    if (e >= kE) return;
    const int r = row[e];
    const int pos = atomicAdd(&g_cnt[r], 1);
    g_cols[pos] = col[e];
}

// h = relu(x@enc_in_W+eb) -> g_h; hc = relu(x@clf_in_W+cb) -> g_hc. MFMA, K=64.
// Reads fp32 x directly; converts to bf16 in-register while staging to LDS.
__global__ __launch_bounds__(256) void input_proj_mfma(
    const float* __restrict__ x,
    const float* __restrict__ eb, const float* __restrict__ cb) {
    __shared__ __hip_bfloat16 xs[64][72];
    __shared__ __hip_bfloat16 ob[64][264];
    const int t = threadIdx.x, lane = t & 63, w = t >> 6;
    const int node0 = blockIdx.x * 64;
#pragma unroll
    for (int it = 0; it < 4; it++) {
        int idx = t + it * 256;          // float4 index; 1024 = 64 rows x 16/row
        int r = idx >> 4, c = idx & 15;
        float4 v = make_float4(0.f, 0.f, 0.f, 0.f);
        if (node0 + r < kN) v = ((const float4*)x)[(size_t)(node0 + r) * 16 + c];
        union { uint2 u; __hip_bfloat16 h[4]; } o;
        o.h[0] = __float2bfloat16(v.x); o.h[1] = __float2bfloat16(v.y);
        o.h[2] = __float2bfloat16(v.z); o.h[3] = __float2bfloat16(v.w);
        *(uint2*)(&xs[r][c * 4]) = o.u;
    }
    __syncthreads();
    const int q = lane >> 4, cidx = lane & 15;
    f32x4 acc[4][4] = {};
    const uint4* pk = (const uint4*)(g_pk + (w >= 2 ? PK_CLF_IN : PK_ENC_IN));
#pragma unroll
    for (int k0 = 0; k0 < 2; k0++) {
        FragCast a[4], b[4];
#pragma unroll
        for (int mt = 0; mt < 4; mt++)
            a[mt].u = *(const uint4*)(&xs[mt * 16 + cidx][k0 * 32 + q * 8]);
#pragma unroll
        for (int nt = 0; nt < 4; nt++)
            b[nt].u = pk[(size_t)(k0 * 8 + (w & 1) * 4 + nt) * 64 + lane];
#pragma unroll
        for (int mt = 0; mt < 4; mt++)
#pragma unroll
            for (int nt = 0; nt < 4; nt++)
                acc[mt][nt] = __builtin_amdgcn_mfma_f32_16x16x32_bf16(
                    a[mt].f, b[nt].f, acc[mt][nt], 0, 0, 0);
    }
    const float* bp = (w >= 2) ? cb : eb;
#pragma unroll
    for (int nt = 0; nt < 4; nt++) {
        const int mcol = (w & 1) * 64 + nt * 16 + cidx;
        const float bv = bp[mcol];
#pragma unroll
        for (int mt = 0; mt < 4; mt++)
#pragma unroll
            for (int r = 0; r < 4; r++)
                ob[mt * 16 + q * 4 + r][w * 64 + nt * 16 + cidx] =
                    __float2bfloat16(fmaxf(acc[mt][nt][r] + bv, 0.f));
    }
    __syncthreads();
#pragma unroll
    for (int it = 0; it < 8; it++) {
        int idx = t + it * 256;
        int r = idx >> 5, c = idx & 31;
        uint4 v = *(const uint4*)(&ob[r][c * 8]);
        if (c < 16) ((uint4*)(g_h  + (size_t)(node0 + r) * kD))[c]      = v;
        else        ((uint4*)(g_hc + (size_t)(node0 + r) * kD))[c - 16] = v;
    }
}

#define AGG_ACC(v, wt) \
    a0 = fmaf(bflo(v.x), wt, a0); a1 = fmaf(bfhi(v.x), wt, a1); \
    a2 = fmaf(bflo(v.y), wt, a2); a3 = fmaf(bfhi(v.y), wt, a3); \
    a4 = fmaf(bflo(v.z), wt, a4); a5 = fmaf(bfhi(v.z), wt, a5); \
    a6 = fmaf(bflo(v.w), wt, a6); a7 = fmaf(bfhi(v.w), wt, a7);
#define AGG_SUM(v) \
    a0 += bflo(v.x); a1 += bfhi(v.x); a2 += bflo(v.y); a3 += bfhi(v.y); \
    a4 += bflo(v.z); a5 += bfhi(v.z); a6 += bflo(v.w); a7 += bfhi(v.w);

// CSR aggregation: z[n] = h[n] + sum_j h[col[j]]*att?. 16 lanes/node (uint4 = 8
// dims each), 16 nodes/block, edge loop unrolled x8 -> 8 row-gathers in flight
// per lane. No LDS -> full occupancy.
__global__ __launch_bounds__(256) void agg_csr_kernel(int src_sel, int use_att) {
    const int t = threadIdx.x;
    const int node = blockIdx.x * 16 + (t >> 4);
    const int li = t & 15;
    const uint4* __restrict__ src = (const uint4*)bsel(src_sel);
    float a0 = 0.f, a1 = 0.f, a2 = 0.f, a3 = 0.f, a4 = 0.f, a5 = 0.f, a6 = 0.f, a7 = 0.f;
    if (node < kN) {
        const uint4 sv = src[(size_t)node * 16 + li];  // self (GIN eps=0)
        a0 = bflo(sv.x); a1 = bfhi(sv.x); a2 = bflo(sv.y); a3 = bfhi(sv.y);
        a4 = bflo(sv.z); a5 = bfhi(sv.z); a6 = bflo(sv.w); a7 = bfhi(sv.w);
        const int beg = g_rowptr[node], end = g_rowptr[node + 1];
        int j = beg;
        if (use_att) {
            for (; j + 8 <= end; j += 8) {
                uint4 v0 = src[(size_t)g_cols[j    ] * 16 + li];
                uint4 v1 = src[(size_t)g_cols[j + 1] * 16 + li];
                uint4 v2 = src[(size_t)g_cols[j + 2] * 16 + li];
                uint4 v3 = src[(size_t)g_cols[j + 3] * 16 + li];
                uint4 v4 = src[(size_t)g_cols[j + 4] * 16 + li];
                uint4 v5 = src[(size_t)g_cols[j + 5] * 16 + li];
                uint4 v6 = src[(size_t)g_cols[j + 6] * 16 + li];
                uint4 v7 = src[(size_t)g_cols[j + 7] * 16 + li];
                const float w0 = g_atts[j],     w1 = g_atts[j + 1];
                const float w2 = g_atts[j + 2], w3 = g_atts[j + 3];
                const float w4 = g_atts[j + 4], w5 = g_atts[j + 5];
                const float w6 = g_atts[j + 6], w7 = g_atts[j + 7];
                AGG_ACC(v0, w0) AGG_ACC(v1, w1) AGG_ACC(v2, w2) AGG_ACC(v3, w3)
                AGG_ACC(v4, w4) AGG_ACC(v5, w5) AGG_ACC(v6, w6) AGG_ACC(v7, w7)
            }
            for (; j < end; j++) {
                const uint4 v = src[(size_t)g_cols[j] * 16 + li];
                const float wt = g_atts[j];
                AGG_ACC(v, wt)
            }
        } else {
            for (; j + 8 <= end; j += 8) {
                uint4 v0 = src[(size_t)g_cols[j    ] * 16 + li];
                uint4 v1 = src[(size_t)g_cols[j + 1] * 16 + li];
                uint4 v2 = src[(size_t)g_cols[j + 2] * 16 + li];
                uint4 v3 = src[(size_t)g_cols[j + 3] * 16 + li];
                uint4 v4 = src[(size_t)g_cols[j + 4] * 16 + li];
                uint4 v5 = src[(size_t)g_cols[j + 5] * 16 + li];
                uint4 v6 = src[(size_t)g_cols[j + 6] * 16 + li];
                uint4 v7 = src[(size_t)g_cols[j + 7] * 16 + li];
                AGG_SUM(v0) AGG_SUM(v1) AGG_SUM(v2) AGG_SUM(v3)
                AGG_SUM(v4) AGG_SUM(v5) AGG_SUM(v6) AGG_SUM(v7)
            }
            for (; j < end; j++) {
                const uint4 v = src[(size_t)g_cols[j] * 16 + li];
                AGG_SUM(v)
            }
        }
    }
    union { uint4 u; __hip_bfloat16 h[8]; } o;
    o.h[0] = __float2bfloat16(a0); o.h[1] = __float2bfloat16(a1);
    o.h[2] = __float2bfloat16(a2); o.h[3] = __float2bfloat16(a3);
    o.h[4] = __float2bfloat16(a4); o.h[5] = __float2bfloat16(a5);
    o.h[6] = __float2bfloat16(a6); o.h[7] = __float2bfloat16(a7);
    ((uint4*)g_z)[(size_t)node * 16 + li] = o.u;
}

// MFMA GIN MLP: h_dst = [relu]( relu(z @ W1 + b1) @ W2 + b2 ). 64 nodes/block.
__global__ __launch_bounds__(256) void gin_mlp_mfma(
    int dst_sel, size_t pkW1off, size_t pkW2off,
    const float* __restrict__ b1, const float* __restrict__ b2, int relu_out) {
    __shared__ __hip_bfloat16 zs[64][136];
    __shared__ __hip_bfloat16 hid[64][264];
    const int t = threadIdx.x, lane = t & 63, w = t >> 6;
    const int node0 = blockIdx.x * 64;
    __hip_bfloat16* hp = bsel(dst_sel);

    {
        const uint4* src = (const uint4*)(g_z + (size_t)node0 * kD);
#pragma unroll
        for (int it = 0; it < 4; it++) {
            int idx = t + it * 256;
            int r = idx >> 4, c = idx & 15;
            *(uint4*)(&zs[r][c * 8]) = src[(size_t)r * 16 + c];
        }
    }
    __syncthreads();

    const int q = lane >> 4, cidx = lane & 15;

    f32x4 acc1[4][4] = {};
    const uint4* pk1 = (const uint4*)(g_pk + pkW1off);
    for (int k0 = 0; k0 < 4; k0++) {
        FragCast a[4], b[4];
#pragma unroll
        for (int mt = 0; mt < 4; mt++)
            a[mt].u = *(const uint4*)(&zs[mt * 16 + cidx][k0 * 32 + q * 8]);
#pragma unroll
        for (int nt = 0; nt < 4; nt++)
            b[nt].u = pk1[(size_t)(k0 * 16 + (w * 4 + nt)) * 64 + lane];
#pragma unroll
        for (int mt = 0; mt < 4; mt++)
#pragma unroll
            for (int nt = 0; nt < 4; nt++)
                acc1[mt][nt] = __builtin_amdgcn_mfma_f32_16x16x32_bf16(
                    a[mt].f, b[nt].f, acc1[mt][nt], 0, 0, 0);
    }
#pragma unroll
    for (int nt = 0; nt < 4; nt++) {
        const int col = w * 64 + nt * 16 + cidx;
        const float bv = b1[col];
#pragma unroll
        for (int mt = 0; mt < 4; mt++)
#pragma unroll
            for (int r = 0; r < 4; r++)
                hid[mt * 16 + q * 4 + r][col] =
                    __float2bfloat16(fmaxf(acc1[mt][nt][r] + bv, 0.f));
    }
    __syncthreads();

    f32x4 acc2[4][2] = {};
    const uint4* pk2 = (const uint4*)(g_pk + pkW2off);
    for (int k0 = 0; k0 < 8; k0++) {
        FragCast a[4], b[2];
#pragma unroll
        for (int mt = 0; mt < 4; mt++)
            a[mt].u = *(const uint4*)(&hid[mt * 16 + cidx][k0 * 32 + q * 8]);
#pragma unroll
        for (int nt = 0; nt < 2; nt++)
            b[nt].u = pk2[(size_t)(k0 * 8 + (w * 2 + nt)) * 64 + lane];
#pragma unroll
        for (int mt = 0; mt < 4; mt++)
#pragma unroll
            for (int nt = 0; nt < 2; nt++)
                acc2[mt][nt] = __builtin_amdgcn_mfma_f32_16x16x32_bf16(
                    a[mt].f, b[nt].f, acc2[mt][nt], 0, 0, 0);
    }
#pragma unroll
    for (int nt = 0; nt < 2; nt++) {
        const int col = w * 32 + nt * 16 + cidx;
        const float bv = b2[col];
#pragma unroll
        for (int mt = 0; mt < 4; mt++)
#pragma unroll
            for (int r = 0; r < 4; r++) {
                float v = acc2[mt][nt][r] + bv;
                if (relu_out) v = fmaxf(v, 0.f);
                zs[mt * 16 + q * 4 + r][col] = __float2bfloat16(v);
            }
    }
    __syncthreads();
    {
        uint4* dst = (uint4*)(hp + (size_t)node0 * kD);
#pragma unroll
        for (int it = 0; it < 4; it++) {
            int idx = t + it * 256;
            int r = idx >> 4, c = idx & 15;
            dst[(size_t)r * 16 + c] = *(const uint4*)(&zs[r][c * 8]);
        }
    }
}

// A/B = enc_h @ attW1_{top,bot} (+b1 for A); enc_h lives in g_h.
__global__ __launch_bounds__(256) void att_dense_mfma(const float* __restrict__ b1) {
    __shared__ __hip_bfloat16 zs[64][136];
    __shared__ __hip_bfloat16 ob[64][264];
    const int t = threadIdx.x, lane = t & 63, w = t >> 6;
    const int node0 = blockIdx.x * 64;
    const int mat = blockIdx.y >> 1, half = blockIdx.y & 1;
    __hip_bfloat16* outp = mat ? g_B : g_A;
    const size_t pkoff = mat ? PK_ATT_BOT : PK_ATT_TOP;

    const uint4* src = (const uint4*)(g_h + (size_t)node0 * kD);
#pragma unroll
    for (int it = 0; it < 4; it++) {
        int idx = t + it * 256;
        int r = idx >> 4, c = idx & 15;
        *(uint4*)(&zs[r][c * 8]) = src[(size_t)r * 16 + c];
    }
    __syncthreads();

    const int q = lane >> 4, cidx = lane & 15;
    f32x4 acc[4][4] = {};
    const uint4* pk = (const uint4*)(g_pk + pkoff);
    for (int k0 = 0; k0 < 4; k0++) {
        FragCast a[4], b[4];
#pragma unroll
        for (int mt = 0; mt < 4; mt++)
            a[mt].u = *(const uint4*)(&zs[mt * 16 + cidx][k0 * 32 + q * 8]);
#pragma unroll
        for (int nt = 0; nt < 4; nt++)
            b[nt].u = pk[(size_t)(k0 * 32 + (half * 16 + w * 4 + nt)) * 64 + lane];
#pragma unroll
        for (int mt = 0; mt < 4; mt++)
#pragma unroll
            for (int nt = 0; nt < 4; nt++)
                acc[mt][nt] = __builtin_amdgcn_mfma_f32_16x16x32_bf16(
                    a[mt].f, b[nt].f, acc[mt][nt], 0, 0, 0);
    }
#pragma unroll
    for (int nt = 0; nt < 4; nt++) {
        const int lcol = w * 64 + nt * 16 + cidx;
        const float bv = (mat == 0) ? b1[half * 256 + lcol] : 0.f;
#pragma unroll
        for (int mt = 0; mt < 4; mt++)
#pragma unroll
            for (int r = 0; r < 4; r++)
                ob[mt * 16 + q * 4 + r][lcol] = __float2bfloat16(acc[mt][nt][r] + bv);
    }
    __syncthreads();
    uint4* dst = (uint4*)(outp + (size_t)node0 * kA4 + half * 256);
#pragma unroll
    for (int it = 0; it < 8; it++) {
        int idx = t + it * 256;
        int r = idx >> 5, c = idx & 31;
        dst[(size_t)r * 64 + c] = *(const uint4*)(&ob[r][c * 8]);
    }
}

#define ATT_DOT(s, bu) \
    s = fmaxf(a0 + bflo(bu.x), 0.f) * w0.x; \
    s = fmaf(fmaxf(a1 + bfhi(bu.x), 0.f), w0.y, s); \
    s = fmaf(fmaxf(a2 + bflo(bu.y), 0.f), w0.z, s); \
    s = fmaf(fmaxf(a3 + bfhi(bu.y), 0.f), w0.w, s); \
    s = fmaf(fmaxf(a4 + bflo(bu.z), 0.f), w1.x, s); \
    s = fmaf(fmaxf(a5 + bfhi(bu.z), 0.f), w1.y, s); \
    s = fmaf(fmaxf(a6 + bflo(bu.w), 0.f), w1.z, s); \
    s = fmaf(fmaxf(a7 + bfhi(bu.w), 0.f), w1.w, s);

// att in CSR order: wave per node, A[node] in registers, gather only B[col].
// Edge loop unrolled x4; the 4 shuffle-reduce chains are interleaved so they
// pipeline through the permute unit while 4 B-rows stay in flight.
__global__ __launch_bounds__(256) void att_edge_csr(
    const float* __restrict__ W2, const float* __restrict__ b2) {
    const int node = blockIdx.x * 4 + (threadIdx.x >> 6);  // grid kN/4 exact
    const int lane = threadIdx.x & 63;
    const int m0 = lane * 8;
    const uint4 au = *(const uint4*)(g_A + (size_t)node * kA4 + m0);
    const float a0 = bflo(au.x), a1 = bfhi(au.x), a2 = bflo(au.y), a3 = bfhi(au.y);
    const float a4 = bflo(au.z), a5 = bfhi(au.z), a6 = bflo(au.w), a7 = bfhi(au.w);
    const float4 w0 = *(const float4*)(W2 + m0);
    const float4 w1 = *(const float4*)(W2 + m0 + 4);
    const float bb = b2[0];
    const int beg = g_rowptr[node], end = g_rowptr[node + 1];
    int j = beg;
    for (; j + 4 <= end; j += 4) {
        const uint4 bu0 = *(const uint4*)(g_B + (size_t)g_cols[j    ] * kA4 + m0);
        const uint4 bu1 = *(const uint4*)(g_B + (size_t)g_cols[j + 1] * kA4 + m0);
        const uint4 bu2 = *(const uint4*)(g_B + (size_t)g_cols[j + 2] * kA4 + m0);
        const uint4 bu3 = *(const uint4*)(g_B + (size_t)g_cols[j + 3] * kA4 + m0);
        float s0, s1, s2, s3;
        ATT_DOT(s0, bu0) ATT_DOT(s1, bu1) ATT_DOT(s2, bu2) ATT_DOT(s3, bu3)
        for (int off = 32; off > 0; off >>= 1) {
            s0 += __shfl_down(s0, off);
            s1 += __shfl_down(s1, off);
            s2 += __shfl_down(s2, off);
            s3 += __shfl_down(s3, off);
        }
        if (lane == 0) {
            g_atts[j]     = 1.f / (1.f + __expf(-(s0 + bb)));
            g_atts[j + 1] = 1.f / (1.f + __expf(-(s1 + bb)));
            g_atts[j + 2] = 1.f / (1.f + __expf(-(s2 + bb)));
            g_atts[j + 3] = 1.f / (1.f + __expf(-(s3 + bb)));
        }
    }
    for (; j < end; j++) {
        const uint4 bu = *(const uint4*)(g_B + (size_t)g_cols[j] * kA4 + m0);
        float s;
        ATT_DOT(s, bu)
        for (int off = 32; off > 0; off >>= 1) s += __shfl_down(s, off);
        if (lane == 0) g_atts[j] = 1.f / (1.f + __expf(-(s + bb)));
    }
}

// Segmented mean-pool over sorted batch; final classifier h lives in g_hc.
__global__ __launch_bounds__(64) void pool_kernel(const int* __restrict__ batch) {
    const int t = threadIdx.x;
    int n = blockIdx.x * PCHUNK;
    const int nend = n + PCHUNK;
    const unsigned* __restrict__ hc = (const unsigned*)g_hc;
    int gcur = batch[n];
    float a0 = 0.f, a1 = 0.f, cv = 0.f;
    for (; n < nend; n++) {
        const int g = batch[n];
        if (g != gcur) {
            atomicAdd(&g_pool[gcur * kD + 2 * t], a0);
            atomicAdd(&g_pool[gcur * kD + 2 * t + 1], a1);
            if (t == 0) atomicAdd(&g_gcnt[gcur], cv);
            a0 = a1 = cv = 0.f; gcur = g;
        }
        unsigned v = hc[(size_t)n * 64 + t];
        a0 += bflo(v); a1 += bfhi(v);
        cv += 1.f;
    }
    atomicAdd(&g_pool[gcur * kD + 2 * t], a0);
    atomicAdd(&g_pool[gcur * kD + 2 * t + 1], a1);
    if (t == 0) atomicAdd(&g_gcnt[gcur], cv);
}

__global__ __launch_bounds__(640) void head_kernel(
    const float* __restrict__ hW, const float* __restrict__ hb,
    float* __restrict__ out) {
    const int t = threadIdx.x;
    const int g = t / kOUT, o = t - g * kOUT;
    const float c = fmaxf(g_gcnt[g], 1.f);
    const float inv = 1.f / c;
    float acc = hb[o];
    for (int k = 0; k < kD; k++)
        acc = fmaf(g_pool[g * kD + k] * inv, hW[k * kOUT + o], acc);
    out[(size_t)g * kOUT + o] = acc;
}

extern "C" void kernel_launch(void* const* d_in, const int* in_sizes, int n_in,
                              void* d_out, int out_size, void* d_ws, size_t ws_size,
                              hipStream_t stream) {
    const float* x        = (const float*)d_in[0];
    const int*   ei       = (const int*)d_in[1];
    const int*   row      = ei;
    const int*   col      = ei + kE;
    const int*   batch    = (const int*)d_in[2];
    const float* enc_in_W = (const float*)d_in[4];
    const float* enc_in_b = (const float*)d_in[5];
    const float* enc_W1   = (const float*)d_in[6];
    const float* enc_b1   = (const float*)d_in[7];
    const float* enc_W2   = (const float*)d_in[8];
    const float* enc_b2   = (const float*)d_in[9];
    const float* att_W1   = (const float*)d_in[10];
    const float* att_b1   = (const float*)d_in[11];
    const float* att_W2   = (const float*)d_in[12];
    const float* att_b2   = (const float*)d_in[13];
    const float* clf_in_W = (const float*)d_in[14];
    const float* clf_in_b = (const float*)d_in[15];
    const float* clf_W1   = (const float*)d_in[16];
    const float* clf_b1   = (const float*)d_in[17];
    const float* clf_W2   = (const float*)d_in[18];
    const float* clf_b2   = (const float*)d_in[19];
    const float* head_W   = (const float*)d_in[20];
    const float* head_b   = (const float*)d_in[21];
    float* out = (float*)d_out;

    const dim3 blk(256);
    const int eblocks = (kE + 255) / 256;

    // ---- weight prepack ----
    SrcPtrs sp;
    for (int l = 0; l < 3; l++) {
        sp.p[0 + l] = enc_W1 + (size_t)l * kD * kH;
        sp.p[3 + l] = enc_W2 + (size_t)l * kH * kD;
        sp.p[6 + l] = clf_W1 + (size_t)l * kD * kH;
        sp.p[9 + l] = clf_W2 + (size_t)l * kH * kD;
    }
    sp.p[12] = att_W1;
    sp.p[13] = att_W1 + (size_t)kD * kA4;
    sp.p[14] = enc_in_W;
    sp.p[15] = clf_in_W;
    prepack_kernel<<<1056, dim3(64), 0, stream>>>(sp);

    // ---- CSR build ----
    zero_prep_kernel<<<(kN + 255) / 256, blk, 0, stream>>>();
    hist_kernel<<<eblocks, blk, 0, stream>>>(row);
    scan_kernel<<<1, dim3(1024), 0, stream>>>();
    scatter_kernel<<<eblocks, blk, 0, stream>>>(row, col);

    input_proj_mfma<<<kNP / 64, blk, 0, stream>>>(x, enc_in_b, clf_in_b);

    // ---- encoder GIN stack (agg: g_h -> g_z; mlp: g_z -> g_h) ----
    for (int l = 0; l < 3; l++) {
        agg_csr_kernel<<<kNP / 16, blk, 0, stream>>>(0, 0);
        gin_mlp_mfma<<<kNP / 64, blk, 0, stream>>>(
            0, PK_ENC_W1(l), PK_ENC_W2(l),
            enc_b1 + (size_t)l * kH, enc_b2 + (size_t)l * kD, (l < 2) ? 1 : 0);
    }

    // ---- edge attention (A/B from g_h; att written in CSR order) ----
    att_dense_mfma<<<dim3(kNP / 64, 4), blk, 0, stream>>>(att_b1);
    att_edge_csr<<<kN / 4, blk, 0, stream>>>(att_W2, att_b2);

    // ---- classifier GIN stack (agg: g_hc -> g_z; mlp: g_z -> g_hc) ----
    for (int l = 0; l < 3; l++) {
        agg_csr_kernel<<<kNP / 16, blk, 0, stream>>>(1, 1);
        gin_mlp_mfma<<<kNP / 64, blk, 0, stream>>>(
            1, PK_CLF_W1(l), PK_CLF_W2(l),
            clf_b1 + (size_t)l * kH, clf_b2 + (size_t)l * kD, (l < 2) ? 1 : 0);
    }

    // ---- mean pool + head ----
    pool_kernel<<<kN / PCHUNK, dim3(64), 0, stream>>>(batch);
    head_kernel<<<1, dim3(kG * kOUT), 0, stream>>>(head_W, head_b, out);
}

// Round 9
// 643.117 us; speedup vs baseline: 1.1775x; 1.1775x over previous
//
#include <hip/hip_runtime.h>
#include <hip/hip_bf16.h>
#include <cstddef>

#define kN 50000
#define kNP 50048   // padded to 64*782
#define kE 500000
#define kG 64
#define kDIN 64
#define kD 128
#define kH 256   // 2*D
#define kA4 512  // 4*D
#define kOUT 10
#define PCHUNK 200
#define SBLK 196    // scan blocks: 196*256 = 50176 >= kN

typedef __attribute__((ext_vector_type(8))) short bfrag_t;
typedef __attribute__((ext_vector_type(4))) float f32x4;
union FragCast { uint4 u; bfrag_t f; };

// ---- static device scratch (rewritten per call) ----
__device__ __attribute__((aligned(16))) __hip_bfloat16 g_h [(size_t)kNP * kD];
__device__ __attribute__((aligned(16))) __hip_bfloat16 g_hc[(size_t)kNP * kD];
__device__ __attribute__((aligned(16))) __hip_bfloat16 g_z [(size_t)kNP * kD];  // agg scratch
__device__ __attribute__((aligned(16))) __hip_bfloat16 g_A [(size_t)kNP * kA4];
__device__ __attribute__((aligned(16))) __hip_bfloat16 g_B [(size_t)kNP * kA4];
__device__ __attribute__((aligned(16))) __hip_bfloat16 g_pk[1056 * 512];  // packed MFMA B-frags
__device__ float g_atts[kE];   // edge weights, CSR order
__device__ int   g_rowptr[kN + 1];
__device__ int   g_cnt[kN];
__device__ int   g_tmp[SBLK * 256];  // scan: exclusive-in-block prefixes
__device__ int   g_bsum[256];        // scan: per-block totals
__device__ int   g_cols[kE];
__device__ float g_pool[kG * kD];
__device__ float g_gcnt[kG];

__device__ inline float bflo(unsigned u) { union { unsigned i; float f; } c; c.i = u << 16; return c.f; }
__device__ inline float bfhi(unsigned u) { union { unsigned i; float f; } c; c.i = u & 0xffff0000u; return c.f; }
__device__ inline __hip_bfloat16* bsel(int s) { return s == 0 ? g_h : (s == 1 ? g_hc : g_z); }

// ---- weight prepack: fp32 -> bf16 MFMA B-fragment order ----
// mats: [0..2] encW1(128x256) [3..5] encW2(256x128) [6..8] clfW1 [9..11] clfW2
//       [12] attTop(128x512) [13] attBot(128x512) [14] enc_in(64x128) [15] clf_in(64x128)
struct SrcPtrs { const float* p[16]; };

__global__ __launch_bounds__(64) void prepack_kernel(SrcPtrs sp) {
    const int fs[17] = {0,64,128,192,256,320,384,448,512,576,640,704,768,896,1024,1040,1056};
    const int Ns[16] = {256,256,256,128,128,128,256,256,256,128,128,128,512,512,128,128};
    int f = blockIdx.x;
    int m = 0;
    while (f >= fs[m + 1]) m++;
    const int fl = f - fs[m];
    const int N = Ns[m];
    const int n0 = fl % (N >> 4);
    const int k0 = fl / (N >> 4);
    const int lane = threadIdx.x;
    const int q = lane >> 4, c = lane & 15;
    const float* src = sp.p[m];
    __hip_bfloat16* dst = g_pk + (size_t)f * 512 + lane * 8;
    const int kb = k0 * 32 + q * 8;
    const int n = n0 * 16 + c;
#pragma unroll
    for (int j = 0; j < 8; j++)
        dst[j] = __float2bfloat16(src[(size_t)(kb + j) * N + n]);
}

// packed offsets (bf16 elements)
#define PK_ENC_W1(l) ((size_t)(0   + (l) * 64) * 512)
#define PK_ENC_W2(l) ((size_t)(192 + (l) * 64) * 512)
#define PK_CLF_W1(l) ((size_t)(384 + (l) * 64) * 512)
#define PK_CLF_W2(l) ((size_t)(576 + (l) * 64) * 512)
#define PK_ATT_TOP   ((size_t)768 * 512)
#define PK_ATT_BOT   ((size_t)896 * 512)
#define PK_ENC_IN    ((size_t)1024 * 512)
#define PK_CLF_IN    ((size_t)1040 * 512)

__global__ __launch_bounds__(256) void zero_prep_kernel() {
    const int i = blockIdx.x * 256 + threadIdx.x;
    if (i < kN) g_cnt[i] = 0;
    if (i < kG * kD) g_pool[i] = 0.f;
    if (i < kG) g_gcnt[i] = 0.f;
}

__global__ __launch_bounds__(256) void hist_kernel(const int* __restrict__ row) {
    const int e = blockIdx.x * 256 + threadIdx.x;
    if (e < kE) atomicAdd(&g_cnt[row[e]], 1);
}

// ---- hierarchical scan (replaces the 84 µs single-block scan) ----
// scan1: per-block exclusive scan of g_cnt -> g_tmp, block total -> g_bsum.
__global__ __launch_bounds__(256) void scan1_kernel() {
    __shared__ int sh[256];
    const int t = threadIdx.x;
    const int i = blockIdx.x * 256 + t;
    const int c = (i < kN) ? g_cnt[i] : 0;
    sh[t] = c;
    __syncthreads();
    int v = c;
    for (int off = 1; off < 256; off <<= 1) {
        int add = (t >= off) ? sh[t - off] : 0;
        __syncthreads();
        v += add;
        sh[t] = v;
        __syncthreads();
    }
    g_tmp[i] = v - c;                 // exclusive within block
    if (t == 255) g_bsum[blockIdx.x] = v;
}

// scan2: single block exclusive scan of g_bsum[SBLK].
__global__ __launch_bounds__(256) void scan2_kernel() {
    __shared__ int sh[256];
    const int t = threadIdx.x;
    const int c = (t < SBLK) ? g_bsum[t] : 0;
    sh[t] = c;
    __syncthreads();
    int v = c;
    for (int off = 1; off < 256; off <<= 1) {
        int add = (t >= off) ? sh[t - off] : 0;
        __syncthreads();
        v += add;
        sh[t] = v;
        __syncthreads();
    }
    if (t < SBLK) g_bsum[t] = v - c;  // exclusive
}

// scan3: rowptr[i] = tmp[i] + bsum[block]; also init cursor copy.
__global__ __launch_bounds__(256) void scan3_kernel() {
    const int i = blockIdx.x * 256 + threadIdx.x;
    const int v = g_tmp[i] + g_bsum[blockIdx.x];
    if (i <= kN) g_rowptr[i] = v;     // i==kN gets total == kE
    if (i < kN) g_cnt[i] = v;         // scatter cursor
}

__global__ __launch_bounds__(256) void scatter_kernel(
    const int* __restrict__ row, const int* __restrict__ col) {
    const int e = blockIdx.x * 256 + threadIdx.x;
    if (e >= kE) return;
    const int r = row[e];
    const int pos = atomicAdd(&g_cnt[r], 1);
    g_cols[pos] = col[e];
}

// h = relu(x@enc_in_W+eb) -> g_h; hc = relu(x@clf_in_W+cb) -> g_hc. MFMA, K=64.
__global__ __launch_bounds__(256) void input_proj_mfma(
    const float* __restrict__ x,
    const float* __restrict__ eb, const float* __restrict__ cb) {
    __shared__ __hip_bfloat16 xs[64][72];
    __shared__ __hip_bfloat16 ob[64][264];
    const int t = threadIdx.x, lane = t & 63, w = t >> 6;
    const int node0 = blockIdx.x * 64;
#pragma unroll
    for (int it = 0; it < 4; it++) {
        int idx = t + it * 256;          // float4 index; 1024 = 64 rows x 16/row
        int r = idx >> 4, c = idx & 15;
        float4 v = make_float4(0.f, 0.f, 0.f, 0.f);
        if (node0 + r < kN) v = ((const float4*)x)[(size_t)(node0 + r) * 16 + c];
        union { uint2 u; __hip_bfloat16 h[4]; } o;
        o.h[0] = __float2bfloat16(v.x); o.h[1] = __float2bfloat16(v.y);
        o.h[2] = __float2bfloat16(v.z); o.h[3] = __float2bfloat16(v.w);
        *(uint2*)(&xs[r][c * 4]) = o.u;
    }
    __syncthreads();
    const int q = lane >> 4, cidx = lane & 15;
    f32x4 acc[4][4] = {};
    const uint4* pk = (const uint4*)(g_pk + (w >= 2 ? PK_CLF_IN : PK_ENC_IN));
#pragma unroll
    for (int k0 = 0; k0 < 2; k0++) {
        FragCast a[4], b[4];
#pragma unroll
        for (int mt = 0; mt < 4; mt++)
            a[mt].u = *(const uint4*)(&xs[mt * 16 + cidx][k0 * 32 + q * 8]);
#pragma unroll
        for (int nt = 0; nt < 4; nt++)
            b[nt].u = pk[(size_t)(k0 * 8 + (w & 1) * 4 + nt) * 64 + lane];
#pragma unroll
        for (int mt = 0; mt < 4; mt++)
#pragma unroll
            for (int nt = 0; nt < 4; nt++)
                acc[mt][nt] = __builtin_amdgcn_mfma_f32_16x16x32_bf16(
                    a[mt].f, b[nt].f, acc[mt][nt], 0, 0, 0);
    }
    const float* bp = (w >= 2) ? cb : eb;
#pragma unroll
    for (int nt = 0; nt < 4; nt++) {
        const int mcol = (w & 1) * 64 + nt * 16 + cidx;
        const float bv = bp[mcol];
#pragma unroll
        for (int mt = 0; mt < 4; mt++)
#pragma unroll
            for (int r = 0; r < 4; r++)
                ob[mt * 16 + q * 4 + r][w * 64 + nt * 16 + cidx] =
                    __float2bfloat16(fmaxf(acc[mt][nt][r] + bv, 0.f));
    }
    __syncthreads();
#pragma unroll
    for (int it = 0; it < 8; it++) {
        int idx = t + it * 256;
        int r = idx >> 5, c = idx & 31;
        uint4 v = *(const uint4*)(&ob[r][c * 8]);
        if (c < 16) ((uint4*)(g_h  + (size_t)(node0 + r) * kD))[c]      = v;
        else        ((uint4*)(g_hc + (size_t)(node0 + r) * kD))[c - 16] = v;
    }
}

#define AGG_ACC(v, wt) \
    a0 = fmaf(bflo(v.x), wt, a0); a1 = fmaf(bfhi(v.x), wt, a1); \
    a2 = fmaf(bflo(v.y), wt, a2); a3 = fmaf(bfhi(v.y), wt, a3); \
    a4 = fmaf(bflo(v.z), wt, a4); a5 = fmaf(bfhi(v.z), wt, a5); \
    a6 = fmaf(bflo(v.w), wt, a6); a7 = fmaf(bfhi(v.w), wt, a7);
#define AGG_SUM(v) \
    a0 += bflo(v.x); a1 += bfhi(v.x); a2 += bflo(v.y); a3 += bfhi(v.y); \
    a4 += bflo(v.z); a5 += bfhi(v.z); a6 += bflo(v.w); a7 += bfhi(v.w);

// CSR aggregation: z[n] = h[n] + sum_j h[col[j]]*att?. 16 lanes/node (uint4 = 8
// dims each), 16 nodes/block, edge loop unrolled x4 (x8 regressed in R8:
// register pressure). No LDS -> full occupancy.
__global__ __launch_bounds__(256) void agg_csr_kernel(int src_sel, int use_att) {
    const int t = threadIdx.x;
    const int node = blockIdx.x * 16 + (t >> 4);
    const int li = t & 15;
    const uint4* __restrict__ src = (const uint4*)bsel(src_sel);
    float a0 = 0.f, a1 = 0.f, a2 = 0.f, a3 = 0.f, a4 = 0.f, a5 = 0.f, a6 = 0.f, a7 = 0.f;
    if (node < kN) {
        const uint4 sv = src[(size_t)node * 16 + li];  // self (GIN eps=0)
        a0 = bflo(sv.x); a1 = bfhi(sv.x); a2 = bflo(sv.y); a3 = bfhi(sv.y);
        a4 = bflo(sv.z); a5 = bfhi(sv.z); a6 = bflo(sv.w); a7 = bfhi(sv.w);
        const int beg = g_rowptr[node], end = g_rowptr[node + 1];
        int j = beg;
        if (use_att) {
            for (; j + 4 <= end; j += 4) {
                uint4 v0 = src[(size_t)g_cols[j    ] * 16 + li];
                uint4 v1 = src[(size_t)g_cols[j + 1] * 16 + li];
                uint4 v2 = src[(size_t)g_cols[j + 2] * 16 + li];
                uint4 v3 = src[(size_t)g_cols[j + 3] * 16 + li];
                const float w0 = g_atts[j],     w1 = g_atts[j + 1];
                const float w2 = g_atts[j + 2], w3 = g_atts[j + 3];
                AGG_ACC(v0, w0) AGG_ACC(v1, w1) AGG_ACC(v2, w2) AGG_ACC(v3, w3)
            }
            for (; j < end; j++) {
                const uint4 v = src[(size_t)g_cols[j] * 16 + li];
                const float wt = g_atts[j];
                AGG_ACC(v, wt)
            }
        } else {
            for (; j + 4 <= end; j += 4) {
                uint4 v0 = src[(size_t)g_cols[j    ] * 16 + li];
                uint4 v1 = src[(size_t)g_cols[j + 1] * 16 + li];
                uint4 v2 = src[(size_t)g_cols[j + 2] * 16 + li];
                uint4 v3 = src[(size_t)g_cols[j + 3] * 16 + li];
                AGG_SUM(v0) AGG_SUM(v1) AGG_SUM(v2) AGG_SUM(v3)
            }
            for (; j < end; j++) {
                const uint4 v = src[(size_t)g_cols[j] * 16 + li];
                AGG_SUM(v)
            }
        }
    }
    union { uint4 u; __hip_bfloat16 h[8]; } o;
    o.h[0] = __float2bfloat16(a0); o.h[1] = __float2bfloat16(a1);
    o.h[2] = __float2bfloat16(a2); o.h[3] = __float2bfloat16(a3);
    o.h[4] = __float2bfloat16(a4); o.h[5] = __float2bfloat16(a5);
    o.h[6] = __float2bfloat16(a6); o.h[7] = __float2bfloat16(a7);
    ((uint4*)g_z)[(size_t)node * 16 + li] = o.u;
}

// MFMA GIN MLP: h_dst = [relu]( relu(z @ W1 + b1) @ W2 + b2 ). 64 nodes/block.
__global__ __launch_bounds__(256) void gin_mlp_mfma(
    int dst_sel, size_t pkW1off, size_t pkW2off,
    const float* __restrict__ b1, const float* __restrict__ b2, int relu_out) {
    __shared__ __hip_bfloat16 zs[64][136];
    __shared__ __hip_bfloat16 hid[64][264];
    const int t = threadIdx.x, lane = t & 63, w = t >> 6;
    const int node0 = blockIdx.x * 64;
    __hip_bfloat16* hp = bsel(dst_sel);

    {
        const uint4* src = (const uint4*)(g_z + (size_t)node0 * kD);
#pragma unroll
        for (int it = 0; it < 4; it++) {
            int idx = t + it * 256;
            int r = idx >> 4, c = idx & 15;
            *(uint4*)(&zs[r][c * 8]) = src[(size_t)r * 16 + c];
        }
    }
    __syncthreads();

    const int q = lane >> 4, cidx = lane & 15;

    f32x4 acc1[4][4] = {};
    const uint4* pk1 = (const uint4*)(g_pk + pkW1off);
    for (int k0 = 0; k0 < 4; k0++) {
        FragCast a[4], b[4];
#pragma unroll
        for (int mt = 0; mt < 4; mt++)
            a[mt].u = *(const uint4*)(&zs[mt * 16 + cidx][k0 * 32 + q * 8]);
#pragma unroll
        for (int nt = 0; nt < 4; nt++)
            b[nt].u = pk1[(size_t)(k0 * 16 + (w * 4 + nt)) * 64 + lane];
#pragma unroll
        for (int mt = 0; mt < 4; mt++)
#pragma unroll
            for (int nt = 0; nt < 4; nt++)
                acc1[mt][nt] = __builtin_amdgcn_mfma_f32_16x16x32_bf16(
                    a[mt].f, b[nt].f, acc1[mt][nt], 0, 0, 0);
    }
#pragma unroll
    for (int nt = 0; nt < 4; nt++) {
        const int col = w * 64 + nt * 16 + cidx;
        const float bv = b1[col];
#pragma unroll
        for (int mt = 0; mt < 4; mt++)
#pragma unroll
            for (int r = 0; r < 4; r++)
                hid[mt * 16 + q * 4 + r][col] =
                    __float2bfloat16(fmaxf(acc1[mt][nt][r] + bv, 0.f));
    }
    __syncthreads();

    f32x4 acc2[4][2] = {};
    const uint4* pk2 = (const uint4*)(g_pk + pkW2off);
    for (int k0 = 0; k0 < 8; k0++) {
        FragCast a[4], b[2];
#pragma unroll
        for (int mt = 0; mt < 4; mt++)
            a[mt].u = *(const uint4*)(&hid[mt * 16 + cidx][k0 * 32 + q * 8]);
#pragma unroll
        for (int nt = 0; nt < 2; nt++)
            b[nt].u = pk2[(size_t)(k0 * 8 + (w * 2 + nt)) * 64 + lane];
#pragma unroll
        for (int mt = 0; mt < 4; mt++)
#pragma unroll
            for (int nt = 0; nt < 2; nt++)
                acc2[mt][nt] = __builtin_amdgcn_mfma_f32_16x16x32_bf16(
                    a[mt].f, b[nt].f, acc2[mt][nt], 0, 0, 0);
    }
#pragma unroll
    for (int nt = 0; nt < 2; nt++) {
        const int col = w * 32 + nt * 16 + cidx;
        const float bv = b2[col];
#pragma unroll
        for (int mt = 0; mt < 4; mt++)
#pragma unroll
            for (int r = 0; r < 4; r++) {
                float v = acc2[mt][nt][r] + bv;
                if (relu_out) v = fmaxf(v, 0.f);
                zs[mt * 16 + q * 4 + r][col] = __float2bfloat16(v);
            }
    }
    __syncthreads();
    {
        uint4* dst = (uint4*)(hp + (size_t)node0 * kD);
#pragma unroll
        for (int it = 0; it < 4; it++) {
            int idx = t + it * 256;
            int r = idx >> 4, c = idx & 15;
            dst[(size_t)r * 16 + c] = *(const uint4*)(&zs[r][c * 8]);
        }
    }
}

// A/B = enc_h @ attW1_{top,bot} (+b1 for A); enc_h lives in g_h.
__global__ __launch_bounds__(256) void att_dense_mfma(const float* __restrict__ b1) {
    __shared__ __hip_bfloat16 zs[64][136];
    __shared__ __hip_bfloat16 ob[64][264];
    const int t = threadIdx.x, lane = t & 63, w = t >> 6;
    const int node0 = blockIdx.x * 64;
    const int mat = blockIdx.y >> 1, half = blockIdx.y & 1;
    __hip_bfloat16* outp = mat ? g_B : g_A;
    const size_t pkoff = mat ? PK_ATT_BOT : PK_ATT_TOP;

    const uint4* src = (const uint4*)(g_h + (size_t)node0 * kD);
#pragma unroll
    for (int it = 0; it < 4; it++) {
        int idx = t + it * 256;
        int r = idx >> 4, c = idx & 15;
        *(uint4*)(&zs[r][c * 8]) = src[(size_t)r * 16 + c];
    }
    __syncthreads();

    const int q = lane >> 4, cidx = lane & 15;
    f32x4 acc[4][4] = {};
    const uint4* pk = (const uint4*)(g_pk + pkoff);
    for (int k0 = 0; k0 < 4; k0++) {
        FragCast a[4], b[4];
#pragma unroll
        for (int mt = 0; mt < 4; mt++)
            a[mt].u = *(const uint4*)(&zs[mt * 16 + cidx][k0 * 32 + q * 8]);
#pragma unroll
        for (int nt = 0; nt < 4; nt++)
            b[nt].u = pk[(size_t)(k0 * 32 + (half * 16 + w * 4 + nt)) * 64 + lane];
#pragma unroll
        for (int mt = 0; mt < 4; mt++)
#pragma unroll
            for (int nt = 0; nt < 4; nt++)
                acc[mt][nt] = __builtin_amdgcn_mfma_f32_16x16x32_bf16(
                    a[mt].f, b[nt].f, acc[mt][nt], 0, 0, 0);
    }
#pragma unroll
    for (int nt = 0; nt < 4; nt++) {
        const int lcol = w * 64 + nt * 16 + cidx;
        const float bv = (mat == 0) ? b1[half * 256 + lcol] : 0.f;
#pragma unroll
        for (int mt = 0; mt < 4; mt++)
#pragma unroll
            for (int r = 0; r < 4; r++)
                ob[mt * 16 + q * 4 + r][lcol] = __float2bfloat16(acc[mt][nt][r] + bv);
    }
    __syncthreads();
    uint4* dst = (uint4*)(outp + (size_t)node0 * kA4 + half * 256);
#pragma unroll
    for (int it = 0; it < 8; it++) {
        int idx = t + it * 256;
        int r = idx >> 5, c = idx & 31;
        dst[(size_t)r * 64 + c] = *(const uint4*)(&ob[r][c * 8]);
    }
}

#define ATT_DOT(s, bu) \
    s = fmaxf(a0 + bflo(bu.x), 0.f) * w0.x; \
    s = fmaf(fmaxf(a1 + bfhi(bu.x), 0.f), w0.y, s); \
    s = fmaf(fmaxf(a2 + bflo(bu.y), 0.f), w0.z, s); \
    s = fmaf(fmaxf(a3 + bfhi(bu.y), 0.f), w0.w, s); \
    s = fmaf(fmaxf(a4 + bflo(bu.z), 0.f), w1.x, s); \
    s = fmaf(fmaxf(a5 + bfhi(bu.z), 0.f), w1.y, s); \
    s = fmaf(fmaxf(a6 + bflo(bu.w), 0.f), w1.z, s); \
    s = fmaf(fmaxf(a7 + bfhi(bu.w), 0.f), w1.w, s);

// att in CSR order: wave per node, A[node] in registers, gather only B[col].
__global__ __launch_bounds__(256) void att_edge_csr(
    const float* __restrict__ W2, const float* __restrict__ b2) {
    const int node = blockIdx.x * 4 + (threadIdx.x >> 6);  // grid kN/4 exact
    const int lane = threadIdx.x & 63;
    const int m0 = lane * 8;
    const uint4 au = *(const uint4*)(g_A + (size_t)node * kA4 + m0);
    const float a0 = bflo(au.x), a1 = bfhi(au.x), a2 = bflo(au.y), a3 = bfhi(au.y);
    const float a4 = bflo(au.z), a5 = bfhi(au.z), a6 = bflo(au.w), a7 = bfhi(au.w);
    const float4 w0 = *(const float4*)(W2 + m0);
    const float4 w1 = *(const float4*)(W2 + m0 + 4);
    const float bb = b2[0];
    const int beg = g_rowptr[node], end = g_rowptr[node + 1];
    int j = beg;
    for (; j + 4 <= end; j += 4) {
        const uint4 bu0 = *(const uint4*)(g_B + (size_t)g_cols[j    ] * kA4 + m0);
        const uint4 bu1 = *(const uint4*)(g_B + (size_t)g_cols[j + 1] * kA4 + m0);
        const uint4 bu2 = *(const uint4*)(g_B + (size_t)g_cols[j + 2] * kA4 + m0);
        const uint4 bu3 = *(const uint4*)(g_B + (size_t)g_cols[j + 3] * kA4 + m0);
        float s0, s1, s2, s3;
        ATT_DOT(s0, bu0) ATT_DOT(s1, bu1) ATT_DOT(s2, bu2) ATT_DOT(s3, bu3)
        for (int off = 32; off > 0; off >>= 1) {
            s0 += __shfl_down(s0, off);
            s1 += __shfl_down(s1, off);
            s2 += __shfl_down(s2, off);
            s3 += __shfl_down(s3, off);
        }
        if (lane == 0) {
            g_atts[j]     = 1.f / (1.f + __expf(-(s0 + bb)));
            g_atts[j + 1] = 1.f / (1.f + __expf(-(s1 + bb)));
            g_atts[j + 2] = 1.f / (1.f + __expf(-(s2 + bb)));
            g_atts[j + 3] = 1.f / (1.f + __expf(-(s3 + bb)));
        }
    }
    for (; j < end; j++) {
        const uint4 bu = *(const uint4*)(g_B + (size_t)g_cols[j] * kA4 + m0);
        float s;
        ATT_DOT(s, bu)
        for (int off = 32; off > 0; off >>= 1) s += __shfl_down(s, off);
        if (lane == 0) g_atts[j] = 1.f / (1.f + __expf(-(s + bb)));
    }
}

// Segmented mean-pool over sorted batch; final classifier h lives in g_hc.
__global__ __launch_bounds__(64) void pool_kernel(const int* __restrict__ batch) {
    const int t = threadIdx.x;
    int n = blockIdx.x * PCHUNK;
    const int nend = n + PCHUNK;
    const unsigned* __restrict__ hc = (const unsigned*)g_hc;
    int gcur = batch[n];
    float a0 = 0.f, a1 = 0.f, cv = 0.f;
    for (; n < nend; n++) {
        const int g = batch[n];
        if (g != gcur) {
            atomicAdd(&g_pool[gcur * kD + 2 * t], a0);
            atomicAdd(&g_pool[gcur * kD + 2 * t + 1], a1);
            if (t == 0) atomicAdd(&g_gcnt[gcur], cv);
            a0 = a1 = cv = 0.f; gcur = g;
        }
        unsigned v = hc[(size_t)n * 64 + t];
        a0 += bflo(v); a1 += bfhi(v);
        cv += 1.f;
    }
    atomicAdd(&g_pool[gcur * kD + 2 * t], a0);
    atomicAdd(&g_pool[gcur * kD + 2 * t + 1], a1);
    if (t == 0) atomicAdd(&g_gcnt[gcur], cv);
}

__global__ __launch_bounds__(640) void head_kernel(
    const float* __restrict__ hW, const float* __restrict__ hb,
    float* __restrict__ out) {
    const int t = threadIdx.x;
    const int g = t / kOUT, o = t - g * kOUT;
    const float c = fmaxf(g_gcnt[g], 1.f);
    const float inv = 1.f / c;
    float acc = hb[o];
    for (int k = 0; k < kD; k++)
        acc = fmaf(g_pool[g * kD + k] * inv, hW[k * kOUT + o], acc);
    out[(size_t)g * kOUT + o] = acc;
}

extern "C" void kernel_launch(void* const* d_in, const int* in_sizes, int n_in,
                              void* d_out, int out_size, void* d_ws, size_t ws_size,
                              hipStream_t stream) {
    const float* x        = (const float*)d_in[0];
    const int*   ei       = (const int*)d_in[1];
    const int*   row      = ei;
    const int*   col      = ei + kE;
    const int*   batch    = (const int*)d_in[2];
    const float* enc_in_W = (const float*)d_in[4];
    const float* enc_in_b = (const float*)d_in[5];
    const float* enc_W1   = (const float*)d_in[6];
    const float* enc_b1   = (const float*)d_in[7];
    const float* enc_W2   = (const float*)d_in[8];
    const float* enc_b2   = (const float*)d_in[9];
    const float* att_W1   = (const float*)d_in[10];
    const float* att_b1   = (const float*)d_in[11];
    const float* att_W2   = (const float*)d_in[12];
    const float* att_b2   = (const float*)d_in[13];
    const float* clf_in_W = (const float*)d_in[14];
    const float* clf_in_b = (const float*)d_in[15];
    const float* clf_W1   = (const float*)d_in[16];
    const float* clf_b1   = (const float*)d_in[17];
    const float* clf_W2   = (const float*)d_in[18];
    const float* clf_b2   = (const float*)d_in[19];
    const float* head_W   = (const float*)d_in[20];
    const float* head_b   = (const float*)d_in[21];
    float* out = (float*)d_out;

    const dim3 blk(256);
    const int eblocks = (kE + 255) / 256;

    // ---- weight prepack ----
    SrcPtrs sp;
    for (int l = 0; l < 3; l++) {
        sp.p[0 + l] = enc_W1 + (size_t)l * kD * kH;
        sp.p[3 + l] = enc_W2 + (size_t)l * kH * kD;
        sp.p[6 + l] = clf_W1 + (size_t)l * kD * kH;
        sp.p[9 + l] = clf_W2 + (size_t)l * kH * kD;
    }
    sp.p[12] = att_W1;
    sp.p[13] = att_W1 + (size_t)kD * kA4;
    sp.p[14] = enc_in_W;
    sp.p[15] = clf_in_W;
    prepack_kernel<<<1056, dim3(64), 0, stream>>>(sp);

    // ---- CSR build (hierarchical scan) ----
    zero_prep_kernel<<<(kN + 255) / 256, blk, 0, stream>>>();
    hist_kernel<<<eblocks, blk, 0, stream>>>(row);
    scan1_kernel<<<SBLK, blk, 0, stream>>>();
    scan2_kernel<<<1, blk, 0, stream>>>();
    scan3_kernel<<<SBLK, blk, 0, stream>>>();
    scatter_kernel<<<eblocks, blk, 0, stream>>>(row, col);

    input_proj_mfma<<<kNP / 64, blk, 0, stream>>>(x, enc_in_b, clf_in_b);

    // ---- encoder GIN stack (agg: g_h -> g_z; mlp: g_z -> g_h) ----
    for (int l = 0; l < 3; l++) {
        agg_csr_kernel<<<kNP / 16, blk, 0, stream>>>(0, 0);
        gin_mlp_mfma<<<kNP / 64, blk, 0, stream>>>(
            0, PK_ENC_W1(l), PK_ENC_W2(l),
            enc_b1 + (size_t)l * kH, enc_b2 + (size_t)l * kD, (l < 2) ? 1 : 0);
    }

    // ---- edge attention (A/B from g_h; att written in CSR order) ----
    att_dense_mfma<<<dim3(kNP / 64, 4), blk, 0, stream>>>(att_b1);
    att_edge_csr<<<kN / 4, blk, 0, stream>>>(att_W2, att_b2);

    // ---- classifier GIN stack (agg: g_hc -> g_z; mlp: g_z -> g_hc) ----
    for (int l = 0; l < 3; l++) {
        agg_csr_kernel<<<kNP / 16, blk, 0, stream>>>(1, 1);
        gin_mlp_mfma<<<kNP / 64, blk, 0, stream>>>(
            1, PK_CLF_W1(l), PK_CLF_W2(l),
            clf_b1 + (size_t)l * kH, clf_b2 + (size_t)l * kD, (l < 2) ? 1 : 0);
    }

    // ---- mean pool + head ----
    pool_kernel<<<kN / PCHUNK, dim3(64), 0, stream>>>(batch);
    head_kernel<<<1, dim3(kG * kOUT), 0, stream>>>(head_W, head_b, out);
}